// Round 1
// baseline (2534.460 us; speedup 1.0000x reference)
//
#include <hip/hip_runtime.h>
#include <math.h>

// Problem constants: B=1, T=3, C=64, H=W=192, K=7, PS=7, WS=8, WS_R=3, WT=1,
// STRIDE0=4 -> NQH=NQW=48, Q=6912, S=2, QS=13824, R=9.

__device__ __forceinline__ int refl(int i, int n) {
    i = (i < 0) ? -i : i;
    return (i >= n) ? (2 * n - 2 - i) : i;
}

// ---------------------------------------------------------------------------
// Stage 1: exact search. One wave per query, 4 waves/block.
// Per chunk (16 channels): stage v0 7x7 patch + v1 14x14 region into LDS.
// lane = (s = lane>>4 row-split, c0 = lane&15 channel). Each lane holds all 64
// delta accumulators; static-u loop keeps acc indices compile-time.
// ---------------------------------------------------------------------------
__global__ __launch_bounds__(256, 2)
void k_exact(const float* __restrict__ vid0, const float* __restrict__ vid1,
             float* __restrict__ out_d, float* __restrict__ out_i,
             int* __restrict__ inds_e)
{
    const int tid  = threadIdx.x;
    const int wv   = tid >> 6;
    const int lane = tid & 63;
    const int s    = lane >> 4;   // 0..3  (row split)
    const int c0   = lane & 15;   // channel within chunk
    const int q    = blockIdx.x * 4 + wv;       // < 6912
    const int tq   = q / 2304;
    const int rem  = q - tq * 2304;
    const int hq   = (rem / 48) * 4;
    const int wq   = (rem - (rem / 48) * 48) * 4;

    // per-wave region: l0 = 16ch x (7 rows x stride 8 + 2) = 928 floats
    //                  l1 = 16ch x (14 rows x stride 18 + 2) = 4064 floats
    __shared__ float lds[4][4992];
    float* l0 = lds[wv];
    float* l1 = lds[wv] + 928;

    float acc[64];
#pragma unroll
    for (int i = 0; i < 64; ++i) acc[i] = 0.f;

    for (int ch = 0; ch < 4; ++ch) {
        __syncthreads();  // WAR: previous chunk readers done before overwrite
        // stage v0 patch chunk: 16 x 7 x 7
        for (int e = lane; e < 784; e += 64) {
            int x  = e % 7;
            int t2 = e / 7;
            int y  = t2 % 7;
            int cc = t2 / 7;
            l0[cc * 58 + y * 8 + x] =
                vid0[((tq * 64 + ch * 16 + cc) * 192 + refl(hq + y - 3, 192)) * 192
                     + refl(wq + x - 3, 192)];
        }
        // stage v1 region chunk: 16 x 14 x 14 (offsets -7..6)
        for (int e = lane; e < 3136; e += 64) {
            int x  = e % 14;
            int t2 = e / 14;
            int y  = t2 % 14;
            int cc = t2 / 14;
            l1[cc * 254 + y * 18 + x] =
                vid1[((tq * 64 + ch * 16 + cc) * 192 + refl(hq + y - 7, 192)) * 192
                     + refl(wq + x - 7, 192)];
        }
        __syncthreads();  // RAW: staging visible to all lanes

        // cache two v0 rows: y0 = s and y0 = s+4 (invalid for s==3 -> zero)
        float v0r0[7], v0r1[7];
        const float* vb = &l0[c0 * 58];
#pragma unroll
        for (int x = 0; x < 7; ++x) v0r0[x] = vb[s * 8 + x];
        {
            int y0b = (s < 3) ? (s + 4) : 6;
#pragma unroll
            for (int x = 0; x < 7; ++x) {
                float v = vb[y0b * 8 + x];
                v0r1[x] = (s < 3) ? v : 0.f;
            }
        }
        // static u loop: v1 row y1 = s+u; j0 uses dhi=u (u<=7), j1 uses dhi=u-4 (u>=4)
#pragma unroll
        for (int u = 0; u < 12; ++u) {
            int y1 = s + u;
            if (y1 > 13) y1 = 13;  // only s==3,u==11; contribution zeroed via v0r1
            const float* rp = &l1[c0 * 254 + y1 * 18];
            float rv[14];
#pragma unroll
            for (int x = 0; x < 14; ++x) rv[x] = rp[x];
            if (u <= 7) {
#pragma unroll
                for (int x0 = 0; x0 < 7; ++x0)
#pragma unroll
                    for (int dw = 0; dw < 8; ++dw)
                        acc[u * 8 + dw] += v0r0[x0] * rv[x0 + dw];
            }
            if (u >= 4) {
#pragma unroll
                for (int x0 = 0; x0 < 7; ++x0)
#pragma unroll
                    for (int dw = 0; dw < 8; ++dw)
                        acc[(u - 4) * 8 + dw] += v0r1[x0] * rv[x0 + dw];
            }
        }
    }

    // transpose-reduce across 64 lanes (row/channel partials -> full dot per delta)
    __syncthreads();
    float* tr = lds[wv];  // 64 x 65
#pragma unroll
    for (int i = 0; i < 64; ++i) tr[i * 65 + lane] = acc[i];
    __syncthreads();
    float tot = 0.f;
#pragma unroll
    for (int j = 0; j < 64; ++j) tot += tr[lane * 65 + j];

    // wave-parallel stable top-7 (tie -> lower delta index, matches lax.top_k)
    bool taken = false;
    for (int k = 0; k < 7; ++k) {
        float cv = taken ? -3.402823e38f : tot;
        int ci = lane;
#pragma unroll
        for (int m = 1; m < 64; m <<= 1) {
            float ov = __shfl_xor(cv, m, 64);
            int   oi = __shfl_xor(ci, m, 64);
            if (ov > cv || (ov == cv && oi < ci)) { cv = ov; ci = oi; }
        }
        if (lane == 0) {
            int dhi = ci >> 3, dwi = ci & 7;
            int hc = refl(hq + dhi - 4, 192);
            int wc = refl(wq + dwi - 4, 192);
            out_d[q * 7 + k] = cv;
            float* o = out_i + (q * 7 + k) * 3;
            o[0] = (float)tq; o[1] = (float)hc; o[2] = (float)wc;
            int* wi = inds_e + (q * 7 + k) * 3;
            wi[0] = tq; wi[1] = hc; wi[2] = wc;
        }
        taken = taken || (lane == ci);
    }
}

// ---------------------------------------------------------------------------
// Stage 2: temporal candidate propagation via rounded flow (round-half-even).
// ---------------------------------------------------------------------------
__global__ void k_temporal(const int* __restrict__ inds_e,
                           const float* __restrict__ fflow,
                           const float* __restrict__ bflow,
                           int* __restrict__ inds_t)
{
    int i = blockIdx.x * blockDim.x + threadIdx.x;  // over Q*K = 48384
    if (i >= 6912 * 7) return;
    int q = i / 7, k = i - 7 * q;
    int t = inds_e[i * 3 + 0], h = inds_e[i * 3 + 1], w = inds_e[i * 3 + 2];
#pragma unroll
    for (int sd = 0; sd < 2; ++sd) {           // sd=0: st=+1 (fflow), sd=1: st=-1 (bflow)
        const float* fl = (sd == 0) ? fflow : bflow;
        int st = (sd == 0) ? 1 : -1;
        float fx = fl[((t * 2 + 0) * 192 + h) * 192 + w];
        float fy = fl[((t * 2 + 1) * 192 + h) * 192 + w];
        int dx = (int)rintf(fx);
        int dy = (int)rintf(fy);
        int tn = t + st;
        tn = tn < 0 ? 0 : (tn > 2 ? 2 : tn);
        int* o = inds_t + ((q * 2 + sd) * 7 + k) * 3;
        o[0] = tn;
        o[1] = refl(h + dy, 192);
        o[2] = refl(w + dx, 192);
    }
}

// ---------------------------------------------------------------------------
// Stage 3: refine. One wave per qs (=q*2+s), 4 waves/block.
// Per chunk (32 channels): v0 patch staged once; per candidate k (unrolled,
// static acc indices) stage 9x9 v1 region and accumulate 3x3 offsets.
// ---------------------------------------------------------------------------
__global__ __launch_bounds__(256, 2)
void k_refine(const float* __restrict__ vid0, const float* __restrict__ vid1,
              const int* __restrict__ inds_t,
              float* __restrict__ out_d, float* __restrict__ out_i)
{
    const int tid  = threadIdx.x;
    const int wv   = tid >> 6;
    const int lane = tid & 63;
    const int s    = lane >> 5;   // 0..1 row split
    const int c0   = lane & 31;   // channel within chunk
    const int qs   = blockIdx.x * 4 + wv;       // < 13824
    const int q    = qs >> 1;
    const int tq   = q / 2304;
    const int rem  = q - tq * 2304;
    const int hq   = (rem / 48) * 4;
    const int wq   = (rem - (rem / 48) * 48) * 4;

    // l0 = 32 x 58 = 1856 floats ; l1 = 32 x (9 rows x stride 10 + 4) = 3008 floats
    __shared__ float lds[4][4864];
    float* l0 = lds[wv];
    float* l1 = lds[wv] + 1856;

    float acc[63];
#pragma unroll
    for (int i = 0; i < 63; ++i) acc[i] = 0.f;

    for (int ch = 0; ch < 2; ++ch) {
        __syncthreads();
        for (int e = lane; e < 1568; e += 64) {     // 32 x 7 x 7
            int x  = e % 7;
            int t2 = e / 7;
            int y  = t2 % 7;
            int cc = t2 / 7;
            l0[cc * 58 + y * 8 + x] =
                vid0[((tq * 64 + ch * 32 + cc) * 192 + refl(hq + y - 3, 192)) * 192
                     + refl(wq + x - 3, 192)];
        }
        __syncthreads();
        // cache v0 rows y0 = s + 2j (j=0..3); y0==7 invalid -> zero
        float v0c[4][7];
#pragma unroll
        for (int j = 0; j < 4; ++j) {
            int y0 = s + 2 * j;
            bool ok = (y0 < 7);
            int y0c = ok ? y0 : 6;
#pragma unroll
            for (int x = 0; x < 7; ++x) {
                float v = l0[c0 * 58 + y0c * 8 + x];
                v0c[j][x] = ok ? v : 0.f;
            }
        }
#pragma unroll
        for (int k = 0; k < 7; ++k) {
            const int* it = inds_t + (qs * 7 + k) * 3;
            int tc = it[0], hcn = it[1], wcn = it[2];
            __syncthreads();  // WAR vs previous k readers
            for (int e = lane; e < 2592; e += 64) {   // 32 x 9 x 9 (offsets -4..4)
                int x  = e % 9;
                int t2 = e / 9;
                int y  = t2 % 9;
                int cc = t2 / 9;
                l1[cc * 94 + y * 10 + x] =
                    vid1[((tc * 64 + ch * 32 + cc) * 192 + refl(hcn + y - 4, 192)) * 192
                         + refl(wcn + x - 4, 192)];
            }
            __syncthreads();
#pragma unroll
            for (int u = 0; u < 9; ++u) {             // v1 row y1 = s + u
                int y1 = s + u;
                if (y1 > 8) y1 = 8;                    // s==1,u==8: zeroed via v0c[3]
                const float* rp = &l1[c0 * 94 + y1 * 10];
                float rv[9];
#pragma unroll
                for (int x = 0; x < 9; ++x) rv[x] = rp[x];
#pragma unroll
                for (int j = 0; j < 4; ++j) {
                    const int dri = u - 2 * j;         // static after unroll
                    if (dri >= 0 && dri <= 2) {
#pragma unroll
                        for (int x0 = 0; x0 < 7; ++x0)
#pragma unroll
                            for (int dc = 0; dc < 3; ++dc)
                                acc[k * 9 + dri * 3 + dc] += v0c[j][x0] * rv[x0 + dc];
                    }
                }
            }
        }
    }

    // transpose-reduce 63 candidates across 64 lanes
    __syncthreads();
    float* tr = lds[wv];  // 63 x 65 = 4095 <= 4864
#pragma unroll
    for (int i = 0; i < 63; ++i) tr[i * 65 + lane] = acc[i];
    __syncthreads();
    int rrow = (lane < 63) ? lane : 62;
    float tot = 0.f;
#pragma unroll
    for (int j = 0; j < 64; ++j) tot += tr[rrow * 65 + j];
    if (lane == 63) tot = -3.402823e38f;

    bool taken = false;
    for (int kk = 0; kk < 7; ++kk) {
        float cv = taken ? -3.402823e38f : tot;
        int ci = lane;
#pragma unroll
        for (int m = 1; m < 64; m <<= 1) {
            float ov = __shfl_xor(cv, m, 64);
            int   oi = __shfl_xor(ci, m, 64);
            if (ov > cv || (ov == cv && oi < ci)) { cv = ov; ci = oi; }
        }
        if (lane == 0) {
            int k = ci / 9, r = ci - 9 * k;
            int dri = r / 3, dci = r - 3 * dri;
            const int* it = inds_t + (qs * 7 + k) * 3;
            int tc = it[0], hcn = it[1], wcn = it[2];
            int row = 6912 + qs;
            out_d[row * 7 + kk] = cv;
            float* o = out_i + (row * 7 + kk) * 3;
            o[0] = (float)tc;
            o[1] = (float)refl(hcn + dri - 1, 192);
            o[2] = (float)refl(wcn + dci - 1, 192);
        }
        taken = taken || (lane == ci);
    }
}

// ---------------------------------------------------------------------------
extern "C" void kernel_launch(void* const* d_in, const int* in_sizes, int n_in,
                              void* d_out, int out_size, void* d_ws, size_t ws_size,
                              hipStream_t stream)
{
    const float* vid0  = (const float*)d_in[0];
    const float* vid1  = (const float*)d_in[1];
    const float* fflow = (const float*)d_in[2];
    const float* bflow = (const float*)d_in[3];

    float* out   = (float*)d_out;
    float* out_d = out;              // 20736*7 dists
    float* out_i = out + 145152;     // 20736*7*3 inds (as float)

    int* ws      = (int*)d_ws;
    int* inds_e  = ws;               // 6912*7*3 ints
    int* inds_t  = ws + 145152;      // 13824*7*3 ints

    k_exact<<<1728, 256, 0, stream>>>(vid0, vid1, out_d, out_i, inds_e);
    k_temporal<<<(6912 * 7 + 255) / 256, 256, 0, stream>>>(inds_e, fflow, bflow, inds_t);
    k_refine<<<3456, 256, 0, stream>>>(vid0, vid1, inds_t, out_d, out_i);
}